// Round 6
// baseline (120.724 us; speedup 1.0000x reference)
//
#include <hip/hip_runtime.h>
#include <hip/hip_fp16.h>
#include <math.h>

#define BN_EPS 1e-5f

constexpr int B_ = 4, N_ = 16384, C_ = 64, K_ = 16, O_ = 64;
constexpr int ROWS = B_ * N_;            // 65536
constexpr int RPB_A = 128;               // rows per block, pass A
constexpr int NBLK_A = ROWS / RPB_A;     // 512
constexpr int RPB_B = 64;                // rows per block, pass B
constexpr int NBLK_B = ROWS / RPB_B;     // 1024

// Native clang vector types for __builtin_nontemporal_* (HIP_vector_type
// classes are rejected by the builtin).
typedef float  vf4 __attribute__((ext_vector_type(4)));
typedef int    vi4 __attribute__((ext_vector_type(4)));

__device__ __forceinline__ float4 nt_load4(const float* p) {
    vf4 v = __builtin_nontemporal_load((const vf4*)p);
    return make_float4(v.x, v.y, v.z, v.w);
}
__device__ __forceinline__ void nt_store4(float* p, float4 v) {
    vf4 t; t.x = v.x; t.y = v.y; t.z = v.z; t.w = v.w;
    __builtin_nontemporal_store(t, (vf4*)p);
}

// 4 halfs = 8 bytes, one dwordx2 access
struct __align__(8) H4 { __half2 a, b; };

__device__ __forceinline__ float4 h4_to_f4(H4 h) {
    const float2 p01 = __half22float2(h.a);
    const float2 p23 = __half22float2(h.b);
    return make_float4(p01.x, p01.y, p23.x, p23.y);
}
__device__ __forceinline__ H4 f4_to_h4(float4 v) {
    H4 h;
    h.a = __floats2half2_rn(v.x, v.y);
    h.b = __floats2half2_rn(v.z, v.w);
    return h;
}

// ---------------------------------------------------------------------------
// Pass A: y1h[r][o] = x[r]·(W1[o]-W2[o])  (fp16 storage),
//         y2h[r][o] = x[r]·W2[o]          (fp16 storage)
//
// 8 rows x 4 outs per thread, 128 rows/block, VALU-bound GEMM from LDS.
// Both outputs fp16: 16 MB written (was 32 fp32); pass_b's per-batch y2
// slice (2.1 MB) is XCD-L2-resident.
// ---------------------------------------------------------------------------
__global__ __launch_bounds__(256) void pass_a(const float* __restrict__ x,
                                              const float* __restrict__ w,
                                              __half* __restrict__ y1h,
                                              __half* __restrict__ y2h) {
    __shared__ __align__(16) float xs[64 * 132];  // [c][row], stride 132
    __shared__ __align__(16) float w1m[64 * 64];  // [c][o] = (W1-W2)^T
    __shared__ __align__(16) float w2s[64 * 64];  // [c][o] = W2^T
    const int tid = threadIdx.x;

    const int blk = blockIdx.x;
    const int xcd = blk & 7;
    const int bt = xcd >> 1;                         // batch for this XCD pair
    const int slot = ((blk >> 3) << 1) | (xcd & 1);  // 0..127 within batch
    const long base = (long)bt * N_ + (long)slot * RPB_A;

    // Stage W transposed; LDS writes contiguous in o (conflict-free).
    for (int i = tid; i < 64 * 16; i += 256) {
        const int o = i & 63;
        const int c4 = i >> 6;  // 0..15
        const float4 wa = *(const float4*)&w[o * 128 + c4 * 4];
        const float4 wb = *(const float4*)&w[o * 128 + 64 + c4 * 4];
        w1m[(c4 * 4 + 0) * 64 + o] = wa.x - wb.x;
        w1m[(c4 * 4 + 1) * 64 + o] = wa.y - wb.y;
        w1m[(c4 * 4 + 2) * 64 + o] = wa.z - wb.z;
        w1m[(c4 * 4 + 3) * 64 + o] = wa.w - wb.w;
        w2s[(c4 * 4 + 0) * 64 + o] = wb.x;
        w2s[(c4 * 4 + 1) * 64 + o] = wb.y;
        w2s[(c4 * 4 + 2) * 64 + o] = wb.z;
        w2s[(c4 * 4 + 3) * 64 + o] = wb.w;
    }

    // Stage x transposed (coalesced nt float4 reads; x is single-use).
    const float* xsrc = x + base * 64;
    for (int i = tid; i < RPB_A * 16; i += 256) {
        const int row = i >> 4;  // 0..127
        const int c4 = i & 15;
        const float4 v = nt_load4(xsrc + i * 4);
        xs[(c4 * 4 + 0) * 132 + row] = v.x;
        xs[(c4 * 4 + 1) * 132 + row] = v.y;
        xs[(c4 * 4 + 2) * 132 + row] = v.z;
        xs[(c4 * 4 + 3) * 132 + row] = v.w;
    }
    __syncthreads();

    const int o0 = (tid & 15) * 4;   // 16 o-groups
    const int r0 = (tid >> 4) * 8;   // 16 row-groups of 8
    float a1[8][4] = {{0.f}};
    float a2[8][4] = {{0.f}};

#pragma unroll 4
    for (int c = 0; c < 64; ++c) {
        const float4 xv0 = *(const float4*)&xs[c * 132 + r0];
        const float4 xv1 = *(const float4*)&xs[c * 132 + r0 + 4];
        const float4 w1v = *(const float4*)&w1m[c * 64 + o0];
        const float4 w2v = *(const float4*)&w2s[c * 64 + o0];
        const float xr[8] = {xv0.x, xv0.y, xv0.z, xv0.w,
                             xv1.x, xv1.y, xv1.z, xv1.w};
#pragma unroll
        for (int r = 0; r < 8; ++r) {
            a1[r][0] = fmaf(xr[r], w1v.x, a1[r][0]);
            a1[r][1] = fmaf(xr[r], w1v.y, a1[r][1]);
            a1[r][2] = fmaf(xr[r], w1v.z, a1[r][2]);
            a1[r][3] = fmaf(xr[r], w1v.w, a1[r][3]);
            a2[r][0] = fmaf(xr[r], w2v.x, a2[r][0]);
            a2[r][1] = fmaf(xr[r], w2v.y, a2[r][1]);
            a2[r][2] = fmaf(xr[r], w2v.z, a2[r][2]);
            a2[r][3] = fmaf(xr[r], w2v.w, a2[r][3]);
        }
    }

#pragma unroll
    for (int r = 0; r < 8; ++r) {
        *(H4*)(y1h + (base + r0 + r) * 64 + o0) =
            f4_to_h4(make_float4(a1[r][0], a1[r][1], a1[r][2], a1[r][3]));
        *(H4*)(y2h + (base + r0 + r) * 64 + o0) =
            f4_to_h4(make_float4(a2[r][0], a2[r][1], a2[r][2], a2[r][3]));
    }
}

// ---------------------------------------------------------------------------
// Pass B: h = y1h[row] + y2h[b][idx]; per-row signed extremum over k=16
// (stored fp16 in exth) and per-channel partials. Lane layout:
// lane = ksub*16 + c4. 2-row unroll: 8 gathers in flight; 8 B/lane gathers
// into the 2.1 MB/batch fp16 slice (XCD-L2-resident).
// ---------------------------------------------------------------------------
__global__ __launch_bounds__(256) void pass_b(const __half* __restrict__ y1h,
                                              const __half* __restrict__ y2h,
                                              const int* __restrict__ idx,
                                              const float* __restrict__ gamma,
                                              __half* __restrict__ exth,
                                              float* __restrict__ partial) {
    __shared__ int sidx[RPB_B * K_];  // 1024 ints
    __shared__ float reds[4][64];
    __shared__ float redq[4][64];
    const int tid = threadIdx.x;
    const int blk = blockIdx.x;
    const int xcd = blk & 7;
    const int bt = xcd >> 1;
    const int slot = ((blk >> 3) << 1) | (xcd & 1);  // 0..255
    const long base = (long)bt * N_ + (long)slot * RPB_B;

    {
        vi4 iv = __builtin_nontemporal_load(
            (const vi4*)(idx + base * K_) + tid);
        ((vi4*)sidx)[tid] = iv;
    }

    const int lane = tid & 63;
    const int wv   = tid >> 6;   // wave 0..3
    const int ksub = lane >> 4;  // 0..3
    const int c4   = lane & 15;  // channel quad
    const __half* y2b = y2h + (long)bt * N_ * 64;

    const float4 gm = ((const float4*)gamma)[c4];
    const float4 sgn = make_float4(gm.x >= 0.f ? 1.f : -1.f,
                                   gm.y >= 0.f ? 1.f : -1.f,
                                   gm.z >= 0.f ? 1.f : -1.f,
                                   gm.w >= 0.f ? 1.f : -1.f);
    __syncthreads();

    float4 psum = make_float4(0.f, 0.f, 0.f, 0.f);
    float4 psq  = make_float4(0.f, 0.f, 0.f, 0.f);

    for (int rl = wv; rl < RPB_B; rl += 8) {  // 2 rows per iter (rl, rl+4)
        const long rowA = base + rl;
        const long rowB = base + rl + 4;
        H4 gA[4], gB[4];
#pragma unroll
        for (int kk = 0; kk < 4; ++kk) {
            const int m = sidx[rl * K_ + kk * 4 + ksub];
            gA[kk] = *(const H4*)(y2b + (long)m * 64 + c4 * 4);
        }
#pragma unroll
        for (int kk = 0; kk < 4; ++kk) {
            const int m = sidx[(rl + 4) * K_ + kk * 4 + ksub];
            gB[kk] = *(const H4*)(y2b + (long)m * 64 + c4 * 4);
        }
        const float4 y1A = h4_to_f4(*(const H4*)(y1h + rowA * 64 + c4 * 4));
        const float4 y1B = h4_to_f4(*(const H4*)(y1h + rowB * 64 + c4 * 4));

        float4 eA = make_float4(-3.402823466e+38f, -3.402823466e+38f,
                                -3.402823466e+38f, -3.402823466e+38f);
        float4 eB = eA;
#pragma unroll
        for (int kk = 0; kk < 4; ++kk) {
            const float2 f01 = __half22float2(gA[kk].a);
            const float2 f23 = __half22float2(gA[kk].b);
            const float hx = y1A.x + f01.x, hy = y1A.y + f01.y;
            const float hz = y1A.z + f23.x, hw = y1A.w + f23.y;
            eA.x = fmaxf(eA.x, sgn.x * hx); eA.y = fmaxf(eA.y, sgn.y * hy);
            eA.z = fmaxf(eA.z, sgn.z * hz); eA.w = fmaxf(eA.w, sgn.w * hw);
            psum.x += hx; psum.y += hy; psum.z += hz; psum.w += hw;
            psq.x = fmaf(hx, hx, psq.x); psq.y = fmaf(hy, hy, psq.y);
            psq.z = fmaf(hz, hz, psq.z); psq.w = fmaf(hw, hw, psq.w);
        }
#pragma unroll
        for (int kk = 0; kk < 4; ++kk) {
            const float2 f01 = __half22float2(gB[kk].a);
            const float2 f23 = __half22float2(gB[kk].b);
            const float hx = y1B.x + f01.x, hy = y1B.y + f01.y;
            const float hz = y1B.z + f23.x, hw = y1B.w + f23.y;
            eB.x = fmaxf(eB.x, sgn.x * hx); eB.y = fmaxf(eB.y, sgn.y * hy);
            eB.z = fmaxf(eB.z, sgn.z * hz); eB.w = fmaxf(eB.w, sgn.w * hw);
            psum.x += hx; psum.y += hy; psum.z += hz; psum.w += hw;
            psq.x = fmaf(hx, hx, psq.x); psq.y = fmaf(hy, hy, psq.y);
            psq.z = fmaf(hz, hz, psq.z); psq.w = fmaf(hw, hw, psq.w);
        }
#pragma unroll
        for (int d = 16; d <= 32; d <<= 1) {
            eA.x = fmaxf(eA.x, __shfl_xor(eA.x, d));
            eA.y = fmaxf(eA.y, __shfl_xor(eA.y, d));
            eA.z = fmaxf(eA.z, __shfl_xor(eA.z, d));
            eA.w = fmaxf(eA.w, __shfl_xor(eA.w, d));
            eB.x = fmaxf(eB.x, __shfl_xor(eB.x, d));
            eB.y = fmaxf(eB.y, __shfl_xor(eB.y, d));
            eB.z = fmaxf(eB.z, __shfl_xor(eB.z, d));
            eB.w = fmaxf(eB.w, __shfl_xor(eB.w, d));
        }
        if (ksub == 0) {
            *(H4*)(exth + rowA * 64 + c4 * 4) =
                f4_to_h4(make_float4(sgn.x * eA.x, sgn.y * eA.y,
                                     sgn.z * eA.z, sgn.w * eA.w));
            *(H4*)(exth + rowB * 64 + c4 * 4) =
                f4_to_h4(make_float4(sgn.x * eB.x, sgn.y * eB.y,
                                     sgn.z * eB.z, sgn.w * eB.w));
        }
    }
    // reduce per-lane partial sums over ksub groups
#pragma unroll
    for (int d = 16; d <= 32; d <<= 1) {
        psum.x += __shfl_xor(psum.x, d); psum.y += __shfl_xor(psum.y, d);
        psum.z += __shfl_xor(psum.z, d); psum.w += __shfl_xor(psum.w, d);
        psq.x  += __shfl_xor(psq.x, d);  psq.y  += __shfl_xor(psq.y, d);
        psq.z  += __shfl_xor(psq.z, d);  psq.w  += __shfl_xor(psq.w, d);
    }
    if (ksub == 0) {
        *(float4*)&reds[wv][c4 * 4] = psum;
        *(float4*)&redq[wv][c4 * 4] = psq;
    }
    __syncthreads();
    if (tid < 64) {
        const float s = reds[0][tid] + reds[1][tid] + reds[2][tid] + reds[3][tid];
        const float q = redq[0][tid] + redq[1][tid] + redq[2][tid] + redq[3][tid];
        partial[blk * 128 + tid] = s;
        partial[blk * 128 + 64 + tid] = q;
    }
}

// ---------------------------------------------------------------------------
// Pass C: 64 blocks, one per channel; double-precision reduction of the
// 1024 block partials; emits scale/shift.
// ---------------------------------------------------------------------------
__global__ __launch_bounds__(256) void pass_c(const float* __restrict__ partial,
                                              const float* __restrict__ gamma,
                                              const float* __restrict__ beta,
                                              float* __restrict__ ss) {
    __shared__ double rs[256];
    __shared__ double rq[256];
    const int o = blockIdx.x;
    const int tid = threadIdx.x;
    double as = 0.0, aq = 0.0;
    for (int i = tid; i < NBLK_B; i += 256) {
        as += (double)partial[i * 128 + o];
        aq += (double)partial[i * 128 + 64 + o];
    }
    rs[tid] = as;
    rq[tid] = aq;
    __syncthreads();
    for (int s = 128; s > 0; s >>= 1) {
        if (tid < s) { rs[tid] += rs[tid + s]; rq[tid] += rq[tid + s]; }
        __syncthreads();
    }
    if (tid == 0) {
        const double cnt = (double)B_ * N_ * K_;  // 1,048,576
        double mean = rs[0] / cnt;
        double var = rq[0] / cnt - mean * mean;
        float scale = gamma[o] * (float)(1.0 / sqrt(var + (double)BN_EPS));
        float shift = beta[o] - (float)mean * scale;
        ss[o] = scale;
        ss[64 + o] = shift;
    }
}

// ---------------------------------------------------------------------------
// Pass D: out = relu(scale * exth + shift)  (sign already folded into exth)
// exth is fp16 (8 B/thread load), out fp32 nt store.
// ---------------------------------------------------------------------------
__global__ __launch_bounds__(256) void pass_d(const __half* __restrict__ exth,
                                              const float* __restrict__ ss,
                                              float* __restrict__ out) {
    __shared__ float sscale[64], sshift[64];
    const int tid = threadIdx.x;
    if (tid < 64) { sscale[tid] = ss[tid]; sshift[tid] = ss[64 + tid]; }
    __syncthreads();
    const long total4 = (long)ROWS * 64 / 4;  // 1,048,576 quads
    for (long i = (long)blockIdx.x * 256 + tid; i < total4;
         i += (long)gridDim.x * 256) {
        const int c0 = ((int)i * 4) & 63;
        const float4 e = h4_to_f4(*(const H4*)(exth + i * 4));
        float4 r;
        r.x = fmaxf(fmaf(sscale[c0],     e.x, sshift[c0]),     0.f);
        r.y = fmaxf(fmaf(sscale[c0 + 1], e.y, sshift[c0 + 1]), 0.f);
        r.z = fmaxf(fmaf(sscale[c0 + 2], e.z, sshift[c0 + 2]), 0.f);
        r.w = fmaxf(fmaf(sscale[c0 + 3], e.w, sshift[c0 + 3]), 0.f);
        nt_store4(out + i * 4, r);
    }
}

extern "C" void kernel_launch(void* const* d_in, const int* in_sizes, int n_in,
                              void* d_out, int out_size, void* d_ws, size_t ws_size,
                              hipStream_t stream) {
    const float* x     = (const float*)d_in[0];
    const int*   idx   = (const int*)d_in[1];
    const float* w     = (const float*)d_in[2];
    const float* gamma = (const float*)d_in[3];
    const float* beta  = (const float*)d_in[4];
    float* out = (float*)d_out;

    float* ws = (float*)d_ws;
    __half* y1h     = (__half*)ws;                        // ROWS*64 f16 (8 MB)
    __half* y2h     = (__half*)(ws + (long)ROWS * 32);    // ROWS*64 f16 (8 MB)
    __half* exth    = (__half*)(ws + (long)ROWS * 64);    // ROWS*64 f16 (8 MB)
    float*  partial = ws + (long)ROWS * 96;               // 1024*128 floats
    float*  ss      = partial + (long)NBLK_B * 128;       // 128 floats

    pass_a<<<NBLK_A, 256, 0, stream>>>(x, w, y1h, y2h);
    pass_b<<<NBLK_B, 256, 0, stream>>>(y1h, y2h, idx, gamma, exth, partial);
    pass_c<<<64, 256, 0, stream>>>(partial, gamma, beta, ss);
    pass_d<<<2048, 256, 0, stream>>>(exth, ss, out);
}

// Round 7
// 113.175 us; speedup vs baseline: 1.0667x; 1.0667x over previous
//
#include <hip/hip_runtime.h>
#include <hip/hip_fp16.h>
#include <math.h>

#define BN_EPS 1e-5f

constexpr int B_ = 4, N_ = 16384, C_ = 64, K_ = 16, O_ = 64;
constexpr int ROWS = B_ * N_;            // 65536
constexpr int RPB_A = 128;               // rows per block, pass A
constexpr int NBLK_A = ROWS / RPB_A;     // 512
constexpr int RPB_B = 64;                // rows per block, pass B
constexpr int NBLK_B = ROWS / RPB_B;     // 1024

// Native clang vector types (HIP_vector_type classes are rejected by
// __builtin_nontemporal_* and MFMA intrinsics).
typedef float    vf4   __attribute__((ext_vector_type(4)));
typedef int      vi4   __attribute__((ext_vector_type(4)));
typedef _Float16 f16x4 __attribute__((ext_vector_type(4)));
typedef _Float16 f16x8 __attribute__((ext_vector_type(8)));
typedef float    f32x4 __attribute__((ext_vector_type(4)));

__device__ __forceinline__ float4 nt_load4(const float* p) {
    vf4 v = __builtin_nontemporal_load((const vf4*)p);
    return make_float4(v.x, v.y, v.z, v.w);
}
__device__ __forceinline__ void nt_store4(float* p, float4 v) {
    vf4 t; t.x = v.x; t.y = v.y; t.z = v.z; t.w = v.w;
    __builtin_nontemporal_store(t, (vf4*)p);
}

// 4 halfs = 8 bytes, one dwordx2 access
struct __align__(8) H4 { __half2 a, b; };

__device__ __forceinline__ float4 h4_to_f4(H4 h) {
    const float2 p01 = __half22float2(h.a);
    const float2 p23 = __half22float2(h.b);
    return make_float4(p01.x, p01.y, p23.x, p23.y);
}
__device__ __forceinline__ H4 f4_to_h4(float4 v) {
    H4 h;
    h.a = __floats2half2_rn(v.x, v.y);
    h.b = __floats2half2_rn(v.z, v.w);
    return h;
}

// ---------------------------------------------------------------------------
// Pass A (MFMA): one fused fp16 GEMM, M=ROWS, N=128, K=64.
//   W'[o][c] = W1[o][c]-W2[o][c]  (o<64)   -> y1h
//   W'[64+o][c] = W2[o][c]                 -> y2h
// v_mfma_f32_16x16x32_f16. Verified layouts (learn_hip m89/m91):
//   A: row=lane&15, k=(lane>>4)*8+j ; B: col=lane&15, same k
//   C/D: col=lane&15, row=(lane>>4)*4+reg
// LDS tiles [r][64] fp16, XOR-swizzled at 16B granularity
// (slot ^= r&7) so 16-lane same-slot reads spread across 8 banks.
// 4 waves x (32 rows x 128 cols) per block; 32 MFMA/wave.
// Math moves from 13.7 us of VALU to ~1 us of MFMA: pass becomes
// memory-bound on x read (16 MB) + y1h/y2h write (16 MB).
// ---------------------------------------------------------------------------
__global__ __launch_bounds__(256) void pass_a(const float* __restrict__ x,
                                              const float* __restrict__ w,
                                              __half* __restrict__ y1h,
                                              __half* __restrict__ y2h) {
    __shared__ __align__(16) _Float16 xs[128 * 64];   // x tile, swizzled
    __shared__ __align__(16) _Float16 wsh[128 * 64];  // W' tile, swizzled
    const int tid = threadIdx.x;

    const int blk = blockIdx.x;
    const int xcd = blk & 7;
    const int bt = xcd >> 1;                         // batch for this XCD pair
    const int slot_b = ((blk >> 3) << 1) | (xcd & 1);  // 0..127 within batch
    const long base = (long)bt * N_ + (long)slot_b * RPB_A;

    // Stage W' (128 outs x 64 c) fp16, swizzled. Wave-uniform branch on o.
    for (int i = tid; i < 128 * 16; i += 256) {
        const int o = i >> 4;    // 0..127
        const int c4 = i & 15;   // c quad
        float4 v;
        if (o < 64) {
            const float4 wa = *(const float4*)&w[o * 128 + c4 * 4];
            const float4 wb = *(const float4*)&w[o * 128 + 64 + c4 * 4];
            v = make_float4(wa.x - wb.x, wa.y - wb.y, wa.z - wb.z, wa.w - wb.w);
        } else {
            v = *(const float4*)&w[(o - 64) * 128 + 64 + c4 * 4];
        }
        const int addr = o * 64 + (((c4 >> 1) ^ (o & 7)) << 3) + ((c4 & 1) << 2);
        f16x4 hv;
        hv[0] = (_Float16)v.x; hv[1] = (_Float16)v.y;
        hv[2] = (_Float16)v.z; hv[3] = (_Float16)v.w;
        *(f16x4*)&wsh[addr] = hv;
    }

    // Stage x (128 rows x 64 c) fp16, swizzled; coalesced nt fp32 reads.
    const float* xsrc = x + base * 64;
    for (int i = tid; i < 128 * 16; i += 256) {
        const int row = i >> 4;  // 0..127
        const int c4 = i & 15;
        const float4 v = nt_load4(xsrc + i * 4);
        const int addr = row * 64 + (((c4 >> 1) ^ (row & 7)) << 3) + ((c4 & 1) << 2);
        f16x4 hv;
        hv[0] = (_Float16)v.x; hv[1] = (_Float16)v.y;
        hv[2] = (_Float16)v.z; hv[3] = (_Float16)v.w;
        *(f16x4*)&xs[addr] = hv;
    }
    __syncthreads();

    const int wv   = tid >> 6;       // wave 0..3: rows [wv*32, wv*32+32)
    const int lane = tid & 63;
    const int lrow = lane & 15;
    const int lk   = lane >> 4;      // k-group 0..3
    const int r0   = wv * 32;

    f32x4 acc[2][8];
#pragma unroll
    for (int i = 0; i < 2; ++i)
#pragma unroll
        for (int j = 0; j < 8; ++j)
            acc[i][j] = (f32x4){0.f, 0.f, 0.f, 0.f};

    // A fragments: [row-frag][k-half]; reused across all 8 col-frags.
    f16x8 af[2][2];
#pragma unroll
    for (int rf = 0; rf < 2; ++rf)
#pragma unroll
        for (int kk = 0; kk < 2; ++kk) {
            const int row = r0 + rf * 16 + lrow;
            const int slot = kk * 4 + lk;            // 0..7
            af[rf][kk] = *(const f16x8*)&xs[row * 64 + ((slot ^ (row & 7)) << 3)];
        }

#pragma unroll
    for (int cf = 0; cf < 8; ++cf) {
#pragma unroll
        for (int kk = 0; kk < 2; ++kk) {
            const int o = cf * 16 + lrow;
            const int slot = kk * 4 + lk;
            const f16x8 bfr =
                *(const f16x8*)&wsh[o * 64 + ((slot ^ (o & 7)) << 3)];
            acc[0][cf] = __builtin_amdgcn_mfma_f32_16x16x32_f16(
                af[0][kk], bfr, acc[0][cf], 0, 0, 0);
            acc[1][cf] = __builtin_amdgcn_mfma_f32_16x16x32_f16(
                af[1][kk], bfr, acc[1][cf], 0, 0, 0);
        }
    }

    // Epilogue: C/D frag (col=lane&15, row=lk*4+reg) -> fp16 scalar stores.
    // 16 consecutive lanes write 16 consecutive cols (32B) per row.
#pragma unroll
    for (int rf = 0; rf < 2; ++rf)
#pragma unroll
        for (int cf = 0; cf < 8; ++cf) {
            const int col = cf * 16 + lrow;           // 0..127, uniform side per cf
            __half* dst = (col < 64)
                ? (y1h + (long)col)
                : (y2h + (long)(col - 64));
#pragma unroll
            for (int r = 0; r < 4; ++r) {
                const long row = base + r0 + rf * 16 + lk * 4 + r;
                dst[row * 64] = __float2half(acc[rf][cf][r]);
            }
        }
}

// ---------------------------------------------------------------------------
// Pass B: h = y1h[row] + y2h[b][idx]; per-row signed extremum over k=16
// (stored fp16 in exth) and per-channel partials. Lane layout:
// lane = ksub*16 + c4. 2-row unroll: 8 gathers in flight; 8 B/lane gathers
// into the 2.1 MB/batch fp16 slice (XCD-L2-resident).
// ---------------------------------------------------------------------------
__global__ __launch_bounds__(256) void pass_b(const __half* __restrict__ y1h,
                                              const __half* __restrict__ y2h,
                                              const int* __restrict__ idx,
                                              const float* __restrict__ gamma,
                                              __half* __restrict__ exth,
                                              float* __restrict__ partial) {
    __shared__ int sidx[RPB_B * K_];  // 1024 ints
    __shared__ float reds[4][64];
    __shared__ float redq[4][64];
    const int tid = threadIdx.x;
    const int blk = blockIdx.x;
    const int xcd = blk & 7;
    const int bt = xcd >> 1;
    const int slot = ((blk >> 3) << 1) | (xcd & 1);  // 0..255
    const long base = (long)bt * N_ + (long)slot * RPB_B;

    {
        vi4 iv = __builtin_nontemporal_load(
            (const vi4*)(idx + base * K_) + tid);
        ((vi4*)sidx)[tid] = iv;
    }

    const int lane = tid & 63;
    const int wv   = tid >> 6;   // wave 0..3
    const int ksub = lane >> 4;  // 0..3
    const int c4   = lane & 15;  // channel quad
    const __half* y2b = y2h + (long)bt * N_ * 64;

    const float4 gm = ((const float4*)gamma)[c4];
    const float4 sgn = make_float4(gm.x >= 0.f ? 1.f : -1.f,
                                   gm.y >= 0.f ? 1.f : -1.f,
                                   gm.z >= 0.f ? 1.f : -1.f,
                                   gm.w >= 0.f ? 1.f : -1.f);
    __syncthreads();

    float4 psum = make_float4(0.f, 0.f, 0.f, 0.f);
    float4 psq  = make_float4(0.f, 0.f, 0.f, 0.f);

    for (int rl = wv; rl < RPB_B; rl += 8) {  // 2 rows per iter (rl, rl+4)
        const long rowA = base + rl;
        const long rowB = base + rl + 4;
        H4 gA[4], gB[4];
#pragma unroll
        for (int kk = 0; kk < 4; ++kk) {
            const int m = sidx[rl * K_ + kk * 4 + ksub];
            gA[kk] = *(const H4*)(y2b + (long)m * 64 + c4 * 4);
        }
#pragma unroll
        for (int kk = 0; kk < 4; ++kk) {
            const int m = sidx[(rl + 4) * K_ + kk * 4 + ksub];
            gB[kk] = *(const H4*)(y2b + (long)m * 64 + c4 * 4);
        }
        const float4 y1A = h4_to_f4(*(const H4*)(y1h + rowA * 64 + c4 * 4));
        const float4 y1B = h4_to_f4(*(const H4*)(y1h + rowB * 64 + c4 * 4));

        float4 eA = make_float4(-3.402823466e+38f, -3.402823466e+38f,
                                -3.402823466e+38f, -3.402823466e+38f);
        float4 eB = eA;
#pragma unroll
        for (int kk = 0; kk < 4; ++kk) {
            const float2 f01 = __half22float2(gA[kk].a);
            const float2 f23 = __half22float2(gA[kk].b);
            const float hx = y1A.x + f01.x, hy = y1A.y + f01.y;
            const float hz = y1A.z + f23.x, hw = y1A.w + f23.y;
            eA.x = fmaxf(eA.x, sgn.x * hx); eA.y = fmaxf(eA.y, sgn.y * hy);
            eA.z = fmaxf(eA.z, sgn.z * hz); eA.w = fmaxf(eA.w, sgn.w * hw);
            psum.x += hx; psum.y += hy; psum.z += hz; psum.w += hw;
            psq.x = fmaf(hx, hx, psq.x); psq.y = fmaf(hy, hy, psq.y);
            psq.z = fmaf(hz, hz, psq.z); psq.w = fmaf(hw, hw, psq.w);
        }
#pragma unroll
        for (int kk = 0; kk < 4; ++kk) {
            const float2 f01 = __half22float2(gB[kk].a);
            const float2 f23 = __half22float2(gB[kk].b);
            const float hx = y1B.x + f01.x, hy = y1B.y + f01.y;
            const float hz = y1B.z + f23.x, hw = y1B.w + f23.y;
            eB.x = fmaxf(eB.x, sgn.x * hx); eB.y = fmaxf(eB.y, sgn.y * hy);
            eB.z = fmaxf(eB.z, sgn.z * hz); eB.w = fmaxf(eB.w, sgn.w * hw);
            psum.x += hx; psum.y += hy; psum.z += hz; psum.w += hw;
            psq.x = fmaf(hx, hx, psq.x); psq.y = fmaf(hy, hy, psq.y);
            psq.z = fmaf(hz, hz, psq.z); psq.w = fmaf(hw, hw, psq.w);
        }
#pragma unroll
        for (int d = 16; d <= 32; d <<= 1) {
            eA.x = fmaxf(eA.x, __shfl_xor(eA.x, d));
            eA.y = fmaxf(eA.y, __shfl_xor(eA.y, d));
            eA.z = fmaxf(eA.z, __shfl_xor(eA.z, d));
            eA.w = fmaxf(eA.w, __shfl_xor(eA.w, d));
            eB.x = fmaxf(eB.x, __shfl_xor(eB.x, d));
            eB.y = fmaxf(eB.y, __shfl_xor(eB.y, d));
            eB.z = fmaxf(eB.z, __shfl_xor(eB.z, d));
            eB.w = fmaxf(eB.w, __shfl_xor(eB.w, d));
        }
        if (ksub == 0) {
            *(H4*)(exth + rowA * 64 + c4 * 4) =
                f4_to_h4(make_float4(sgn.x * eA.x, sgn.y * eA.y,
                                     sgn.z * eA.z, sgn.w * eA.w));
            *(H4*)(exth + rowB * 64 + c4 * 4) =
                f4_to_h4(make_float4(sgn.x * eB.x, sgn.y * eB.y,
                                     sgn.z * eB.z, sgn.w * eB.w));
        }
    }
    // reduce per-lane partial sums over ksub groups
#pragma unroll
    for (int d = 16; d <= 32; d <<= 1) {
        psum.x += __shfl_xor(psum.x, d); psum.y += __shfl_xor(psum.y, d);
        psum.z += __shfl_xor(psum.z, d); psum.w += __shfl_xor(psum.w, d);
        psq.x  += __shfl_xor(psq.x, d);  psq.y  += __shfl_xor(psq.y, d);
        psq.z  += __shfl_xor(psq.z, d);  psq.w  += __shfl_xor(psq.w, d);
    }
    if (ksub == 0) {
        *(float4*)&reds[wv][c4 * 4] = psum;
        *(float4*)&redq[wv][c4 * 4] = psq;
    }
    __syncthreads();
    if (tid < 64) {
        const float s = reds[0][tid] + reds[1][tid] + reds[2][tid] + reds[3][tid];
        const float q = redq[0][tid] + redq[1][tid] + redq[2][tid] + redq[3][tid];
        partial[blk * 128 + tid] = s;
        partial[blk * 128 + 64 + tid] = q;
    }
}

// ---------------------------------------------------------------------------
// Pass C: 64 blocks, one per channel; double-precision reduction of the
// 1024 block partials; emits scale/shift.
// ---------------------------------------------------------------------------
__global__ __launch_bounds__(256) void pass_c(const float* __restrict__ partial,
                                              const float* __restrict__ gamma,
                                              const float* __restrict__ beta,
                                              float* __restrict__ ss) {
    __shared__ double rs[256];
    __shared__ double rq[256];
    const int o = blockIdx.x;
    const int tid = threadIdx.x;
    double as = 0.0, aq = 0.0;
    for (int i = tid; i < NBLK_B; i += 256) {
        as += (double)partial[i * 128 + o];
        aq += (double)partial[i * 128 + 64 + o];
    }
    rs[tid] = as;
    rq[tid] = aq;
    __syncthreads();
    for (int s = 128; s > 0; s >>= 1) {
        if (tid < s) { rs[tid] += rs[tid + s]; rq[tid] += rq[tid + s]; }
        __syncthreads();
    }
    if (tid == 0) {
        const double cnt = (double)B_ * N_ * K_;  // 1,048,576
        double mean = rs[0] / cnt;
        double var = rq[0] / cnt - mean * mean;
        float scale = gamma[o] * (float)(1.0 / sqrt(var + (double)BN_EPS));
        float shift = beta[o] - (float)mean * scale;
        ss[o] = scale;
        ss[64 + o] = shift;
    }
}

// ---------------------------------------------------------------------------
// Pass D: out = relu(scale * exth + shift)  (sign already folded into exth)
// exth is fp16 (8 B/thread load), out fp32 nt store.
// ---------------------------------------------------------------------------
__global__ __launch_bounds__(256) void pass_d(const __half* __restrict__ exth,
                                              const float* __restrict__ ss,
                                              float* __restrict__ out) {
    __shared__ float sscale[64], sshift[64];
    const int tid = threadIdx.x;
    if (tid < 64) { sscale[tid] = ss[tid]; sshift[tid] = ss[64 + tid]; }
    __syncthreads();
    const long total4 = (long)ROWS * 64 / 4;  // 1,048,576 quads
    for (long i = (long)blockIdx.x * 256 + tid; i < total4;
         i += (long)gridDim.x * 256) {
        const int c0 = ((int)i * 4) & 63;
        const float4 e = h4_to_f4(*(const H4*)(exth + i * 4));
        float4 r;
        r.x = fmaxf(fmaf(sscale[c0],     e.x, sshift[c0]),     0.f);
        r.y = fmaxf(fmaf(sscale[c0 + 1], e.y, sshift[c0 + 1]), 0.f);
        r.z = fmaxf(fmaf(sscale[c0 + 2], e.z, sshift[c0 + 2]), 0.f);
        r.w = fmaxf(fmaf(sscale[c0 + 3], e.w, sshift[c0 + 3]), 0.f);
        nt_store4(out + i * 4, r);
    }
}

extern "C" void kernel_launch(void* const* d_in, const int* in_sizes, int n_in,
                              void* d_out, int out_size, void* d_ws, size_t ws_size,
                              hipStream_t stream) {
    const float* x     = (const float*)d_in[0];
    const int*   idx   = (const int*)d_in[1];
    const float* w     = (const float*)d_in[2];
    const float* gamma = (const float*)d_in[3];
    const float* beta  = (const float*)d_in[4];
    float* out = (float*)d_out;

    float* ws = (float*)d_ws;
    __half* y1h     = (__half*)ws;                        // ROWS*64 f16 (8 MB)
    __half* y2h     = (__half*)(ws + (long)ROWS * 32);    // ROWS*64 f16 (8 MB)
    __half* exth    = (__half*)(ws + (long)ROWS * 64);    // ROWS*64 f16 (8 MB)
    float*  partial = ws + (long)ROWS * 96;               // 1024*128 floats
    float*  ss      = partial + (long)NBLK_B * 128;       // 128 floats

    pass_a<<<NBLK_A, 256, 0, stream>>>(x, w, y1h, y2h);
    pass_b<<<NBLK_B, 256, 0, stream>>>(y1h, y2h, idx, gamma, exth, partial);
    pass_c<<<64, 256, 0, stream>>>(partial, gamma, beta, ss);
    pass_d<<<2048, 256, 0, stream>>>(exth, ss, out);
}